// Round 7
// baseline (423.260 us; speedup 1.0000x reference)
//
#include <hip/hip_runtime.h>
#include <hip/hip_cooperative_groups.h>
#include <stdint.h>

namespace cg = cooperative_groups;

// Problem constants (fixed by setup_inputs): B=8192, I=512, H=1024
#define BATCH 8192
#define IDIM  512
#define HDIM  1024
#define KDIM  1536          // I + H
#define NDIM  4096          // 4*H
#define NBLK  256           // cooperative grid: 1 block/CU

typedef __bf16 bf16x8 __attribute__((ext_vector_type(8)));
typedef float  f32x4  __attribute__((ext_vector_type(4)));
typedef unsigned short u16x8 __attribute__((ext_vector_type(8)));

__device__ __forceinline__ unsigned short f2bf(float f) {
    union { float f; unsigned u; } v; v.f = f;
    unsigned r = v.u + 0x7fffu + ((v.u >> 16) & 1u);   // RNE
    return (unsigned short)(r >> 16);
}
__device__ __forceinline__ float bf2f(unsigned short u) {
    union { unsigned u; float f; } v; v.u = ((unsigned)u) << 16;
    return v.f;
}
__device__ __forceinline__ float fexp(float x) {      // e^x via v_exp_f32
    return __builtin_amdgcn_exp2f(x * 1.44269504f);
}
__device__ __forceinline__ float sigm(float x) {
    return __builtin_amdgcn_rcpf(1.f + fexp(-x));
}
__device__ __forceinline__ float ftanh(float x) {     // 1 - 2/(e^{2x}+1)
    return 1.f - 2.f * __builtin_amdgcn_rcpf(1.f + fexp(2.f * x));
}

__device__ __forceinline__ void load16(void* lds, const void* g) {
    __builtin_amdgcn_global_load_lds(
        (const __attribute__((address_space(1))) unsigned int*)g,
        (__attribute__((address_space(3))) unsigned int*)lds, 16, 0, 0);
}

// =================== SINGLE COOPERATIVE FUSED KERNEL =======================
// R7: pack -> grid.sync -> gemm(2 tiles/block) -> grid.sync -> epilogue.
// Rationale: across R0-R6, (total - gemm) = 190-202us regardless of large
// pack/ep changes; BW-ideal for pack+ep is ~50us -> most of the residual is
// launch/graph overhead between 3 kernels. One cooperative dispatch deletes
// the boundaries and makes the true GPU time visible as a single dispatch.
// 256 blocks x 512 threads, 128KB LDS -> exactly 1 block/CU, co-resident.
// gemm body = R2's verbatim (best measured: 101us, 45% MfmaUtil), run twice
// per block: pass p tiles (bm fixed, bn + p*2048) -> A-tile L2-hot on pass 1.
__global__ __launch_bounds__(512, 2) void lstm_fused(
        const float* __restrict__ x,   const float* __restrict__ h,
        const float* __restrict__ Wi,  const float* __restrict__ Wh,
        const float* __restrict__ bh,  const float* __restrict__ c,
        const float* __restrict__ gamma, const float* __restrict__ beta,
        unsigned short* __restrict__ A, unsigned short* __restrict__ Wt,
        unsigned short* __restrict__ gates, float* __restrict__ out) {
    __shared__ __align__(16) unsigned short smem[65536];   // 128 KB

    const int t   = threadIdx.x;
    const int bid = blockIdx.x;
    const int wave = t >> 6;
    const int lane = t & 63;

    // ---------------- Phase P: pack A ([x|h] -> bf16) ---------------------
    // 8192*1536/8 = 1,572,864 u16x8 groups = 256*512*12 exactly.
#pragma unroll
    for (int it = 0; it < 12; ++it) {
        int idx = bid * 512 + t + it * (NBLK * 512);
        int row = idx / (KDIM / 8);
        int g8  = idx % (KDIM / 8);          // 0..191
        const float* src = (g8 < IDIM / 8)
                         ? x + (size_t)row * IDIM + g8 * 8
                         : h + (size_t)row * HDIM + (g8 - IDIM / 8) * 8;
        float4 v0 = ((const float4*)src)[0];
        float4 v1 = ((const float4*)src)[1];
        u16x8 o;
        o[0] = f2bf(v0.x); o[1] = f2bf(v0.y); o[2] = f2bf(v0.z); o[3] = f2bf(v0.w);
        o[4] = f2bf(v1.x); o[5] = f2bf(v1.y); o[6] = f2bf(v1.z); o[7] = f2bf(v1.w);
        *(u16x8*)(A + (size_t)idx * 8) = o;
    }
    // ---------------- Phase P: pack Wt (transpose [Wi;Wh]) ----------------
    // 3072 tiles (64n x 32k) = 256 blocks * 12.
    {
        float (*tile)[65] = (float(*)[65])smem;
        int tx = t & 63, ty = t >> 6;        // 64 x 8
        int nl = t >> 3, k4 = (t & 7) * 4;   // 64 n-rows x 8 k-quads
        for (int it = 0; it < 12; ++it) {
            int b  = bid * 12 + it;
            int n0 = (b & 63) * 64;          // 64 n-blocks
            int k0 = (b >> 6) * 32;          // 48 k-blocks
#pragma unroll
            for (int j = 0; j < 4; j++) {
                int k = k0 + ty + 8 * j;
                float v;
                if (k < IDIM) v = Wi[(size_t)k * NDIM + n0 + tx];
                else          v = Wh[(size_t)(k - IDIM) * NDIM + n0 + tx];
                tile[ty + 8 * j][tx] = v;
            }
            __syncthreads();
            ushort4 o;
            o.x = f2bf(tile[k4 + 0][nl]);
            o.y = f2bf(tile[k4 + 1][nl]);
            o.z = f2bf(tile[k4 + 2][nl]);
            o.w = f2bf(tile[k4 + 3][nl]);
            *(ushort4*)(Wt + (size_t)(n0 + nl) * KDIM + k0 + k4) = o;
            __syncthreads();
        }
    }

    cg::this_grid().sync();

    // ---------------- Phase G: GEMM gates = A @ Wt^T (two 256x256 tiles) --
    {
        const int lrow = lane & 15;
        const int quad = lane >> 4;
        const int xcd  = bid & 7;
        const int wm   = (wave & 1) * 128;
        const int wn   = (wave >> 1) * 64;

        // LDS fragment-read offsets: pass-invariant
        int offA[8], offB[4];
#pragma unroll
        for (int mt = 0; mt < 8; mt++) {
            int r = wm + mt * 16 + lrow;
            offA[mt] = (r >> 1) * 64 + (((((r & 1) << 2) | quad) ^ ((r >> 1) & 7)) * 8);
        }
#pragma unroll
        for (int nt = 0; nt < 4; nt++) {
            int r = wn + nt * 16 + lrow;
            offB[nt] = (r >> 1) * 64 + (((((r & 1) << 2) | quad) ^ ((r >> 1) & 7)) * 8);
        }

        for (int p = 0; p < 2; ++p) {
            const int jj = (bid >> 3) + p * 32;            // 0..63
            const int bm = (xcd * 4 + (jj & 3)) * 256;     // same both passes
            const int bn = (jj >> 2) * 256;

            int srcA[2], srcB[2];
#pragma unroll
            for (int j = 0; j < 2; j++) {
                int q   = t + 512 * j;
                int rp  = q >> 3, s = q & 7;
                int xx  = s ^ (rp & 7);
                int row = 2 * rp + (xx >> 2);
                int kc  = xx & 3;
                srcA[j] = (bm + row) * KDIM + kc * 8;
                srcB[j] = (bn + row) * KDIM + kc * 8;
            }

            f32x4 acc[8][4] = {};

#define STAGE(tt) do {                                              \
    unsigned short* _d = smem + (((tt) & 3) << 14);                 \
    const int _ko = (tt) * 32;                                      \
    load16(_d +          t * 8, A  + (size_t)(srcA[0] + _ko));      \
    load16(_d +  4096 +  t * 8, A  + (size_t)(srcA[1] + _ko));      \
    load16(_d +  8192 +  t * 8, Wt + (size_t)(srcB[0] + _ko));      \
    load16(_d + 12288 +  t * 8, Wt + (size_t)(srcB[1] + _ko));      \
} while (0)

            STAGE(0); STAGE(1); STAGE(2);

            const int NT = KDIM / 32;          // 48
            for (int T = 0; T < NT; ++T) {
                if (T < NT - 2)       asm volatile("s_waitcnt vmcnt(8)" ::: "memory");
                else if (T == NT - 2) asm volatile("s_waitcnt vmcnt(4)" ::: "memory");
                else                  asm volatile("s_waitcnt vmcnt(0)" ::: "memory");
                __builtin_amdgcn_s_barrier();
                asm volatile("" ::: "memory");

                const unsigned short* bufA = smem + ((T & 3) << 14);
                const unsigned short* bufB = bufA + 8192;

                bf16x8 a[4], b[4], a2[4];
#pragma unroll
                for (int i = 0; i < 4; i++) a[i] = *(const bf16x8*)(bufA + offA[i]);
#pragma unroll
                for (int i = 0; i < 4; i++) b[i] = *(const bf16x8*)(bufB + offB[i]);
                __builtin_amdgcn_sched_barrier(0);
                if (T + 3 < NT) STAGE(T + 3);
#pragma unroll
                for (int i = 0; i < 4; i++) a2[i] = *(const bf16x8*)(bufA + offA[4 + i]);
                __builtin_amdgcn_sched_barrier(0);

                __builtin_amdgcn_s_setprio(1);
#pragma unroll
                for (int mt = 0; mt < 4; mt++)
#pragma unroll
                    for (int nt = 0; nt < 4; nt++)
                        acc[mt][nt] = __builtin_amdgcn_mfma_f32_16x16x32_bf16(
                            a[mt], b[nt], acc[mt][nt], 0, 0, 0);
                __builtin_amdgcn_sched_barrier(0);
#pragma unroll
                for (int mt = 0; mt < 4; mt++)
#pragma unroll
                    for (int nt = 0; nt < 4; nt++)
                        acc[4 + mt][nt] = __builtin_amdgcn_mfma_f32_16x16x32_bf16(
                            a2[mt], b[nt], acc[4 + mt][nt], 0, 0, 0);
                __builtin_amdgcn_s_setprio(0);
                asm volatile("" ::: "memory");
            }
#undef STAGE

#pragma unroll
            for (int mt = 0; mt < 8; mt++)
#pragma unroll
                for (int nt = 0; nt < 4; nt++) {
                    int row = bm + wm + mt * 16 + quad * 4;
                    int col = bn + wn + nt * 16 + lrow;
#pragma unroll
                    for (int r = 0; r < 4; r++)
                        gates[(size_t)(row + r) * NDIM + col] = f2bf(acc[mt][nt][r]);
                }
        }
    }

    cg::this_grid().sync();

    // ---------------- Phase E: per-row LN + LSTM epilogue -----------------
    // 8192 rows = 4 iters x (256 blocks x 8 waves). Lane l owns cols
    // [16l,16l+16) of all 4 gates; LN reductions are full-wave shuffles.
    for (int it = 0; it < 4; ++it) {
        const int b    = it * (NBLK * 8) + bid * 8 + wave;
        const int col0 = lane * 16;

        const unsigned short* gr = gates + (size_t)b * NDIM;
        float v[4][16];
        float s[4], sq[4];
#pragma unroll
        for (int g = 0; g < 4; g++) {
            const unsigned short* gp = gr + g * HDIM + col0;
            u16x8 ga = *(const u16x8*)gp;
            u16x8 gb = *(const u16x8*)(gp + 8);
            float bb[16];
#pragma unroll
            for (int q = 0; q < 4; q++)
                *(float4*)(bb + 4 * q) = ((const float4*)(bh + g * HDIM + col0))[q];
            float ls = 0.f, lq = 0.f;
#pragma unroll
            for (int j = 0; j < 16; j++) {
                float tv = bf2f(j < 8 ? ga[j] : gb[j - 8]) + bb[j];
                v[g][j] = tv; ls += tv; lq += tv * tv;
            }
            s[g] = ls; sq[g] = lq;
        }
#pragma unroll
        for (int off = 32; off; off >>= 1) {
#pragma unroll
            for (int g = 0; g < 4; g++) {
                s[g]  += __shfl_xor(s[g], off);
                sq[g] += __shfl_xor(sq[g], off);
            }
        }
#pragma unroll
        for (int g = 0; g < 4; g++) {
            const float mu  = s[g] * (1.f / HDIM);
            const float var = sq[g] * (1.f / HDIM) - mu * mu;
            const float rs  = rsqrtf(var + 1e-5f);
            float gm[16], bt[16];
#pragma unroll
            for (int q = 0; q < 4; q++) {
                *(float4*)(gm + 4 * q) = ((const float4*)(gamma + g * HDIM + col0))[q];
                *(float4*)(bt + 4 * q) = ((const float4*)(beta  + g * HDIM + col0))[q];
            }
#pragma unroll
            for (int j = 0; j < 16; j++) {
                float y = (v[g][j] - mu) * rs * gm[j] + bt[j];
                v[g][j] = (g == 2) ? ftanh(y) : sigm(y);
            }
        }
        const size_t base = (size_t)b * HDIM + col0;
#pragma unroll
        for (int q = 0; q < 4; q++) {
            float4 ci = *(const float4*)(c + base + 4 * q);
            float4 cn, hn;
#pragma unroll
            for (int e = 0; e < 4; e++) {
                int j = 4 * q + e;
                float cnv = v[1][j] * ((float*)&ci)[e] + v[0][j] * v[2][j];
                ((float*)&cn)[e] = cnv;
                ((float*)&hn)[e] = v[3][j] * ftanh(cnv);
            }
            *(float4*)(out + base + 4 * q) = hn;                           // h_new
            *(float4*)(out + (size_t)BATCH * HDIM + base + 4 * q) = cn;    // c_new
        }
    }
}

extern "C" void kernel_launch(void* const* d_in, const int* in_sizes, int n_in,
                              void* d_out, int out_size, void* d_ws, size_t ws_size,
                              hipStream_t stream) {
    const float* x     = (const float*)d_in[0];
    const float* h     = (const float*)d_in[1];
    const float* c     = (const float*)d_in[2];
    const float* Wi    = (const float*)d_in[3];
    const float* Wh    = (const float*)d_in[4];
    const float* bh    = (const float*)d_in[5];
    const float* gamma = (const float*)d_in[6];
    const float* beta  = (const float*)d_in[7];
    float* out = (float*)d_out;

    // workspace layout
    unsigned short* A  = (unsigned short*)d_ws;                                        // 25.2 MB
    unsigned short* Wt = (unsigned short*)((char*)d_ws + (size_t)BATCH * KDIM * 2);    // 12.6 MB
    unsigned short* gates = (unsigned short*)((char*)d_ws + (size_t)BATCH * KDIM * 2
                                                          + (size_t)NDIM * KDIM * 2); // 64 MB

    void* args[] = { (void*)&x, (void*)&h, (void*)&Wi, (void*)&Wh,
                     (void*)&bh, (void*)&c, (void*)&gamma, (void*)&beta,
                     (void*)&A, (void*)&Wt, (void*)&gates, (void*)&out };
    hipLaunchCooperativeKernel((const void*)lstm_fused, dim3(NBLK), dim3(512),
                               args, 0, stream);
}